// Round 3
// baseline (1349.224 us; speedup 1.0000x reference)
//
#include <hip/hip_runtime.h>

// LSTM: B=512, T=512, D=128, H=64, O=1. Gate order i,f,g,o.
// Plan:
//   K1: pre[b*T+t][0..255] = x[b,t,:] @ Wih0^T + (bih0+bhh0)   (parallel GEMM)
//   K2: per-batch persistent loop over t: layer-0 cell (z = pre + h0@Whh0^T),
//       then pre1 = h0_t @ Wih1^T + (bih1+bhh1) written IN-PLACE over pre[t].
//   K3: per-batch persistent loop over t: layer-1 cell; final head at the end.
// ws usage: 512*512*256*4 = 268,435,456 bytes (one fp32 pre buffer).

#define T_STEPS 512
#define DIN 128
#define HID 64

__device__ __forceinline__ float sigf(float x) {
    return 1.0f / (1.0f + __expf(-x));
}
// overflow-safe tanh (c can reach ~±150)
__device__ __forceinline__ float tanh_fast(float x) {
    float ax = fabsf(x);
    float e = __expf(-2.0f * ax);
    float r = (1.0f - e) / (1.0f + e);
    return copysignf(r, x);
}

// ---------------- K1: input projection GEMM ----------------
// grid 4096 blocks x 256 thr; tile = 64 rows x 256 cols, K=128.
__global__ __launch_bounds__(256) void k_inproj(
    const float* __restrict__ x, const float* __restrict__ W,
    const float* __restrict__ bih, const float* __restrict__ bhh,
    float* __restrict__ pre)
{
    __shared__ float xs[64][128];
    const int tid = threadIdx.x;
    const long row0 = (long)blockIdx.x * 64;

    const float4* __restrict__ xv = (const float4*)(x + row0 * DIN);
    float4* xsv = (float4*)(&xs[0][0]);
#pragma unroll
    for (int i = 0; i < 8; ++i) xsv[tid + 256 * i] = xv[tid + 256 * i];
    __syncthreads();

    const int tx = tid & 63;
    const int ty = tid >> 6;

    float acc[16][4];
#pragma unroll
    for (int i = 0; i < 16; ++i)
#pragma unroll
        for (int j = 0; j < 4; ++j) acc[i][j] = 0.0f;

#pragma unroll 1
    for (int kc = 0; kc < 16; ++kc) {
        const int k0 = kc * 8;
        float4 w0[4], w1[4];
#pragma unroll
        for (int j = 0; j < 4; ++j) {
            const float* wr = W + (tx + 64 * j) * DIN + k0;
            w0[j] = *(const float4*)wr;
            w1[j] = *(const float4*)(wr + 4);
        }
#pragma unroll
        for (int i = 0; i < 16; ++i) {
            const int r = ty * 16 + i;
            float4 a0 = *(const float4*)(&xs[r][k0]);
            float4 a1 = *(const float4*)(&xs[r][k0 + 4]);
#pragma unroll
            for (int j = 0; j < 4; ++j) {
                float s = acc[i][j];
                s = fmaf(a0.x, w0[j].x, s);
                s = fmaf(a0.y, w0[j].y, s);
                s = fmaf(a0.z, w0[j].z, s);
                s = fmaf(a0.w, w0[j].w, s);
                s = fmaf(a1.x, w1[j].x, s);
                s = fmaf(a1.y, w1[j].y, s);
                s = fmaf(a1.z, w1[j].z, s);
                s = fmaf(a1.w, w1[j].w, s);
                acc[i][j] = s;
            }
        }
    }

    float bsum[4];
#pragma unroll
    for (int j = 0; j < 4; ++j) {
        const int g = tx + 64 * j;
        bsum[j] = bih[g] + bhh[g];
    }
#pragma unroll
    for (int i = 0; i < 16; ++i) {
        const long r = row0 + ty * 16 + i;
        float* pr = pre + r * 256;
#pragma unroll
        for (int j = 0; j < 4; ++j) pr[tx + 64 * j] = acc[i][j] + bsum[j];
    }
}

// ---------------- K2: layer-0 recurrence + fused layer-1 input proj ---------
// grid 512 blocks (1 batch elem each) x 256 thr. Thread tid owns gate column g=tid.
// Whh0[g,:] and Wih1[g,:] live in registers; h0 broadcast from LDS.
__global__ __launch_bounds__(256) void k_rnn0(
    const float* __restrict__ Whh, const float* __restrict__ Wih1,
    const float* __restrict__ bih1, const float* __restrict__ bhh1,
    float* __restrict__ pre)
{
    const int tid = threadIdx.x;
    const int b = blockIdx.x;
    __shared__ __align__(16) float h[64];
    __shared__ float zb[256];

    float4 wh[16], wi[16];
    const float4* whv = (const float4*)(Whh + tid * HID);
    const float4* wiv = (const float4*)(Wih1 + tid * HID);
#pragma unroll
    for (int i = 0; i < 16; ++i) { wh[i] = whv[i]; wi[i] = wiv[i]; }
    const float bias1 = bih1[tid] + bhh1[tid];

    if (tid < 64) h[tid] = 0.0f;
    float c = 0.0f;  // cell state, live in threads tid<64

    float* __restrict__ preb = pre + (long)b * T_STEPS * 256;
    float p = preb[tid];  // t=0, prefetched
    __syncthreads();

    const int gt = tid >> 6;  // 0:i 1:f 2:g 3:o

#pragma unroll 1
    for (int t = 0; t < T_STEPS; ++t) {
        // prefetch next step's pre (hides HBM latency under compute)
        float pn = 0.0f;
        if (t + 1 < T_STEPS) pn = preb[(t + 1) * 256 + tid];

        // phase A: z[g] = pre + h_{t-1} . Whh[g,:]
        float acc = p;
#pragma unroll
        for (int k = 0; k < 16; ++k) {
            float4 hv = *(const float4*)(&h[k * 4]);
            acc = fmaf(hv.x, wh[k].x, acc);
            acc = fmaf(hv.y, wh[k].y, acc);
            acc = fmaf(hv.z, wh[k].z, acc);
            acc = fmaf(hv.w, wh[k].w, acc);
        }
        float a = (gt == 2) ? tanh_fast(acc) : sigf(acc);
        zb[tid] = a;
        __syncthreads();

        // gate stage: threads 0..63 own hidden unit tid
        if (tid < 64) {
            float i_ = zb[tid];
            float f_ = zb[64 + tid];
            float g_ = zb[128 + tid];
            float o_ = zb[192 + tid];
            c = fmaf(f_, c, i_ * g_);
            h[tid] = o_ * tanh_fast(c);
        }
        __syncthreads();

        // phase B: pre1[g] = bias1 + h_t . Wih1[g,:]  (in-place over pre[t])
        float acc2 = bias1;
#pragma unroll
        for (int k = 0; k < 16; ++k) {
            float4 hv = *(const float4*)(&h[k * 4]);
            acc2 = fmaf(hv.x, wi[k].x, acc2);
            acc2 = fmaf(hv.y, wi[k].y, acc2);
            acc2 = fmaf(hv.z, wi[k].z, acc2);
            acc2 = fmaf(hv.w, wi[k].w, acc2);
        }
        preb[t * 256 + tid] = acc2;
        p = pn;
    }
}

// ---------------- K3: layer-1 recurrence + head ----------------
__global__ __launch_bounds__(256) void k_rnn1(
    const float* __restrict__ Whh, const float* __restrict__ Wfc,
    const float* __restrict__ bfc, const float* __restrict__ pre,
    float* __restrict__ out)
{
    const int tid = threadIdx.x;
    const int b = blockIdx.x;
    __shared__ __align__(16) float h[64];
    __shared__ float zb[256];

    float4 wh[16];
    const float4* whv = (const float4*)(Whh + tid * HID);
#pragma unroll
    for (int i = 0; i < 16; ++i) wh[i] = whv[i];

    if (tid < 64) h[tid] = 0.0f;
    float c = 0.0f;

    const float* __restrict__ preb = pre + (long)b * T_STEPS * 256;
    float p = preb[tid];
    __syncthreads();

    const int gt = tid >> 6;

#pragma unroll 1
    for (int t = 0; t < T_STEPS; ++t) {
        float pn = 0.0f;
        if (t + 1 < T_STEPS) pn = preb[(t + 1) * 256 + tid];

        float acc = p;
#pragma unroll
        for (int k = 0; k < 16; ++k) {
            float4 hv = *(const float4*)(&h[k * 4]);
            acc = fmaf(hv.x, wh[k].x, acc);
            acc = fmaf(hv.y, wh[k].y, acc);
            acc = fmaf(hv.z, wh[k].z, acc);
            acc = fmaf(hv.w, wh[k].w, acc);
        }
        float a = (gt == 2) ? tanh_fast(acc) : sigf(acc);
        zb[tid] = a;
        __syncthreads();

        if (tid < 64) {
            float i_ = zb[tid];
            float f_ = zb[64 + tid];
            float g_ = zb[128 + tid];
            float o_ = zb[192 + tid];
            c = fmaf(f_, c, i_ * g_);
            h[tid] = o_ * tanh_fast(c);
        }
        __syncthreads();
        p = pn;
    }

    // head: out[b] = h . Wfc + bfc   (tid<64 is exactly wave 0)
    if (tid < 64) {
        float v = h[tid] * Wfc[tid];
#pragma unroll
        for (int off = 32; off > 0; off >>= 1) v += __shfl_down(v, off);
        if (tid == 0) out[b] = v + bfc[0];
    }
}

extern "C" void kernel_launch(void* const* d_in, const int* in_sizes, int n_in,
                              void* d_out, int out_size, void* d_ws, size_t ws_size,
                              hipStream_t stream)
{
    const float* x    = (const float*)d_in[0];
    const float* Wih0 = (const float*)d_in[1];
    const float* Whh0 = (const float*)d_in[2];
    const float* bih0 = (const float*)d_in[3];
    const float* bhh0 = (const float*)d_in[4];
    const float* Wih1 = (const float*)d_in[5];
    const float* Whh1 = (const float*)d_in[6];
    const float* bih1 = (const float*)d_in[7];
    const float* bhh1 = (const float*)d_in[8];
    const float* Wfc  = (const float*)d_in[9];
    const float* bfc  = (const float*)d_in[10];
    float* out = (float*)d_out;
    float* pre = (float*)d_ws;  // [B*T][256] fp32 = 256 MiB

    k_inproj<<<4096, 256, 0, stream>>>(x, Wih0, bih0, bhh0, pre);
    k_rnn0<<<512, 256, 0, stream>>>(Whh0, Wih1, bih1, bhh1, pre);
    k_rnn1<<<512, 256, 0, stream>>>(Whh1, Wfc, bfc, pre, out);
}

// Round 4
// 1233.025 us; speedup vs baseline: 1.0942x; 1.0942x over previous
//
#include <hip/hip_runtime.h>

// LSTM: B=512, T=512, D=128, H=64, O=1. Gate order i,f,g,o.
//   K1: pre[b*T+t][0..255] = x[b,t,:] @ Wih0^T + (bih0+bhh0)   (parallel GEMM)
//   K2 (fused): per-batch block, layers 0 and 1 skewed by one timestep.
//       Lane-quad owns output column q; each lane a 16-wide quarter of the
//       three dots (Whh0 h0, Wih1 h0, Whh1 h1) -> 12 float4 = 48 weight VGPRs
//       (small enough that the compiler keeps them resident — Round-3's 685us
//       was Wih1 being re-fetched from L2 every step after demotion at VGPR=80).
// ws usage: 512*512*256*4 = 268,435,456 bytes (pre0 buffer, read-only in K2).

#define T_STEPS 512
#define DIN 128
#define HID 64

__device__ __forceinline__ float sigf(float x) {
    return 1.0f / (1.0f + __expf(-x));
}
// overflow-safe tanh (c can reach large magnitude)
__device__ __forceinline__ float tanh_fast(float x) {
    float ax = fabsf(x);
    float e = __expf(-2.0f * ax);
    float r = (1.0f - e) / (1.0f + e);
    return copysignf(r, x);
}
__device__ __forceinline__ float dot4(float4 a, float4 b, float acc) {
    acc = fmaf(a.x, b.x, acc);
    acc = fmaf(a.y, b.y, acc);
    acc = fmaf(a.z, b.z, acc);
    acc = fmaf(a.w, b.w, acc);
    return acc;
}

// ---------------- K1: input projection GEMM ----------------
// grid 4096 blocks x 256 thr; tile = 64 rows x 256 cols, K=128.
__global__ __launch_bounds__(256) void k_inproj(
    const float* __restrict__ x, const float* __restrict__ W,
    const float* __restrict__ bih, const float* __restrict__ bhh,
    float* __restrict__ pre)
{
    __shared__ float xs[64][128];
    const int tid = threadIdx.x;
    const long row0 = (long)blockIdx.x * 64;

    const float4* __restrict__ xv = (const float4*)(x + row0 * DIN);
    float4* xsv = (float4*)(&xs[0][0]);
#pragma unroll
    for (int i = 0; i < 8; ++i) xsv[tid + 256 * i] = xv[tid + 256 * i];
    __syncthreads();

    const int tx = tid & 63;
    const int ty = tid >> 6;

    float acc[16][4];
#pragma unroll
    for (int i = 0; i < 16; ++i)
#pragma unroll
        for (int j = 0; j < 4; ++j) acc[i][j] = 0.0f;

#pragma unroll 1
    for (int kc = 0; kc < 16; ++kc) {
        const int k0 = kc * 8;
        float4 w0[4], w1[4];
#pragma unroll
        for (int j = 0; j < 4; ++j) {
            const float* wr = W + (tx + 64 * j) * DIN + k0;
            w0[j] = *(const float4*)wr;
            w1[j] = *(const float4*)(wr + 4);
        }
#pragma unroll
        for (int i = 0; i < 16; ++i) {
            const int r = ty * 16 + i;
            float4 a0 = *(const float4*)(&xs[r][k0]);
            float4 a1 = *(const float4*)(&xs[r][k0 + 4]);
#pragma unroll
            for (int j = 0; j < 4; ++j) {
                float s = acc[i][j];
                s = dot4(a0, w0[j], s);
                s = dot4(a1, w1[j], s);
                acc[i][j] = s;
            }
        }
    }

    float bsum[4];
#pragma unroll
    for (int j = 0; j < 4; ++j) {
        const int g = tx + 64 * j;
        bsum[j] = bih[g] + bhh[g];
    }
#pragma unroll
    for (int i = 0; i < 16; ++i) {
        const long r = row0 + ty * 16 + i;
        float* pr = pre + r * 256;
#pragma unroll
        for (int j = 0; j < 4; ++j) pr[tx + 64 * j] = acc[i][j] + bsum[j];
    }
}

// ---------------- K2: fused 2-layer recurrence + head ----------------
// grid 512 blocks (1 batch elem) x 1024 thr (16 waves).
// Skew: iteration n computes layer-0 step t=n and layer-1 step t=n-1.
// Loop runs n = 0..T inclusive (layer-0 active n<T, layer-1 active n>=1).
__global__ __launch_bounds__(1024) void k_fused(
    const float* __restrict__ Whh0, const float* __restrict__ Wih1,
    const float* __restrict__ Whh1,
    const float* __restrict__ bih1, const float* __restrict__ bhh1,
    const float* __restrict__ Wfc,  const float* __restrict__ bfc,
    const float* __restrict__ pre,  float* __restrict__ out)
{
    const int tid = threadIdx.x;
    const int b = blockIdx.x;
    const int q  = tid >> 2;   // output column 0..255
    const int qt = tid & 3;    // k-quarter 0..3

    __shared__ __align__(16) float h0s[64];
    __shared__ __align__(16) float h1s[64];
    __shared__ float zb0[256];
    __shared__ float zb1[256];

    // per-thread weight quarters: 12 float4 = 48 VGPRs, coalesced loads (64B/lane)
    float4 w0[4], w1[4], w2[4];
    {
        const float4* p0 = (const float4*)(Whh0 + q * HID + qt * 16);
        const float4* p1 = (const float4*)(Wih1 + q * HID + qt * 16);
        const float4* p2 = (const float4*)(Whh1 + q * HID + qt * 16);
#pragma unroll
        for (int i = 0; i < 4; ++i) { w0[i] = p0[i]; w1[i] = p1[i]; w2[i] = p2[i]; }
    }
    const float bias1 = bih1[q] + bhh1[q];
    const int gt = q >> 6;  // 0:i 1:f 2:g 3:o

    if (tid < 64) { h0s[tid] = 0.0f; h1s[tid] = 0.0f; }
    float c0 = 0.0f;  // lives in tid<64
    float c1 = 0.0f;  // lives in tid 64..127

    const float* __restrict__ preb = pre + (long)b * T_STEPS * 256;
    float pcur = preb[q];          // t = 0
    float pnx  = preb[256 + q];    // t = 1   (depth-2 prefetch)
    __syncthreads();

#pragma unroll 1
    for (int n = 0; n <= T_STEPS; ++n) {
        // prefetch pre0 for t = n+2 (2 iterations of lead to cover HBM latency)
        float pnn = 0.0f;
        if (n + 2 < T_STEPS) pnn = preb[(n + 2) * 256 + q];

        // h0_{n-1}, h1_{n-2} quarter-vectors from LDS (broadcast, conflict-free)
        float4 h0v[4], h1v[4];
        const float4* h0f = (const float4*)h0s;
        const float4* h1f = (const float4*)h1s;
#pragma unroll
        for (int i = 0; i < 4; ++i) { h0v[i] = h0f[qt * 4 + i]; h1v[i] = h1f[qt * 4 + i]; }

        // three quarter-dots, independent 16-FMA chains
        float pA = 0.0f, pB = 0.0f, pC = 0.0f;
#pragma unroll
        for (int i = 0; i < 4; ++i) {
            pA = dot4(w0[i], h0v[i], pA);   // Whh0 . h0
            pB = dot4(w1[i], h0v[i], pB);   // Wih1 . h0
            pC = dot4(w2[i], h1v[i], pC);   // Whh1 . h1
        }
        float s = pB + pC;
        // intra-quad butterfly: all 4 lanes end with full 64-deep sums
        pA += __shfl_xor(pA, 1); pA += __shfl_xor(pA, 2);
        s  += __shfl_xor(s, 1);  s  += __shfl_xor(s, 2);

        if (qt == 0 && n < T_STEPS) {
            float z = pcur + pA;                       // layer-0 preact, t=n
            zb0[q] = (gt == 2) ? tanh_fast(z) : sigf(z);
        }
        if (qt == 1 && n >= 1) {
            float z = bias1 + s;                       // layer-1 preact, t=n-1
            zb1[q] = (gt == 2) ? tanh_fast(z) : sigf(z);
        }
        __syncthreads();

        // gate/cell updates
        if (tid < 64) {
            if (n < T_STEPS) {
                float i_ = zb0[tid], f_ = zb0[64 + tid], g_ = zb0[128 + tid], o_ = zb0[192 + tid];
                c0 = fmaf(f_, c0, i_ * g_);
                h0s[tid] = o_ * tanh_fast(c0);
            }
        } else if (tid < 128) {
            if (n >= 1) {
                const int j = tid - 64;
                float i_ = zb1[j], f_ = zb1[64 + j], g_ = zb1[128 + j], o_ = zb1[192 + j];
                c1 = fmaf(f_, c1, i_ * g_);
                h1s[j] = o_ * tanh_fast(c1);
            }
        }
        __syncthreads();

        pcur = pnx; pnx = pnn;
    }

    // head: out[b] = h1_{T-1} . Wfc + bfc  (wave 0)
    if (tid < 64) {
        float v = h1s[tid] * Wfc[tid];
#pragma unroll
        for (int off = 32; off > 0; off >>= 1) v += __shfl_down(v, off);
        if (tid == 0) out[b] = v + bfc[0];
    }
}

extern "C" void kernel_launch(void* const* d_in, const int* in_sizes, int n_in,
                              void* d_out, int out_size, void* d_ws, size_t ws_size,
                              hipStream_t stream)
{
    const float* x    = (const float*)d_in[0];
    const float* Wih0 = (const float*)d_in[1];
    const float* Whh0 = (const float*)d_in[2];
    const float* bih0 = (const float*)d_in[3];
    const float* bhh0 = (const float*)d_in[4];
    const float* Wih1 = (const float*)d_in[5];
    const float* Whh1 = (const float*)d_in[6];
    const float* bih1 = (const float*)d_in[7];
    const float* bhh1 = (const float*)d_in[8];
    const float* Wfc  = (const float*)d_in[9];
    const float* bfc  = (const float*)d_in[10];
    float* out = (float*)d_out;
    float* pre = (float*)d_ws;  // [B*T][256] fp32 = 256 MiB

    k_inproj<<<4096, 256, 0, stream>>>(x, Wih0, bih0, bhh0, pre);
    k_fused<<<512, 1024, 0, stream>>>(Whh0, Wih1, Whh1, bih1, bhh1, Wfc, bfc, pre, out);
}